// Round 1
// baseline (239.960 us; speedup 1.0000x reference)
//
#include <hip/hip_runtime.h>

#define CHVOL (128*128*128)

// 9 stats: [S_-2, S_-1, S_0(count), S_1, S_2, S_3, S_4, S_5, T=sum x*ln x]
// Branchless: cndmask + fma, no divergent branch.
__device__ __forceinline__ void accum9(float* a, float x) {
    bool nz = (x != 0.0f);
    float u = nz ? __builtin_amdgcn_rcpf(x) : 0.0f;
    float l = nz ? __logf(x) : 0.0f;
    float x2 = x * x;
    float x4 = x2 * x2;
    a[0] = fmaf(u, u, a[0]);
    a[1] += u;
    a[2] += nz ? 1.0f : 0.0f;
    a[3] += x;
    a[4] += x2;
    a[5] = fmaf(x2, x, a[5]);
    a[6] += x4;
    a[7] = fmaf(x4, x, a[7]);
    a[8] = fmaf(x, l, a[8]);
}

// Shuffle-reduce NS stats across the block; leaves 4 per-wave partials in red.
// Caller combines red[t] + red[NS+t] + red[2NS+t] + red[3NS+t] after the sync.
template<int NS>
__device__ __forceinline__ void block_reduce(float* acc, float* red, int t) {
    #pragma unroll
    for (int s = 0; s < NS; ++s) {
        float v = acc[s];
        v += __shfl_down(v, 32, 64);
        v += __shfl_down(v, 16, 64);
        v += __shfl_down(v, 8, 64);
        v += __shfl_down(v, 4, 64);
        v += __shfl_down(v, 2, 64);
        v += __shfl_down(v, 1, 64);
        if ((t & 63) == 0) red[(t >> 6) * NS + s] = v;
    }
    __syncthreads();
}

// Fused: main pass (levels 0-3 in-block, as before) + per-channel device fan-in.
// The 256th block to finish a channel becomes the finisher and runs the old
// k_pyr body inline (levels 4,5 pyramid + least-squares finale), overlapping
// with other channels' main blocks instead of waiting for a second launch.
__global__ __launch_bounds__(256) void k_fused(const float* __restrict__ img,
                                               float* __restrict__ part,
                                               float* __restrict__ l3map,
                                               int* __restrict__ cnt,
                                               const int* __restrict__ bounds,
                                               float* __restrict__ out) {
    __shared__ float zm[256];        // [w4][z''2][x32]
    __shared__ float red[36 * 4];
    __shared__ float sst[54];
    __shared__ float M4[512];
    __shared__ int last;

    const int t  = threadIdx.x;
    const int l  = t & 63, w = t >> 6;
    const int r  = blockIdx.x;        // 0..255
    const int ch = blockIdx.y;        // 0..5
    const int ry = r & 15, rz = r >> 4;
    const float* base = img + (size_t)ch * CHVOL + rz * (8 * 16384) + ry * (8 * 128);

    float acc[36];
    #pragma unroll
    for (int j = 0; j < 36; ++j) acc[j] = 0.0f;

    const int x5 = l & 31;
    const int y  = ((l >> 5) & 1) | (w << 1);   // y in [0,8)
    const float* tbase = base + y * 128 + x5 * 4;

    // i = z slice 0..7. L1 z-pairs merge across (i, i+1); L2 z''-pairs across i-pairs.
    float d0 = 0.0f, d1 = 0.0f;      // L2 partial for z''=0 / z''=1 at (x''=x5, y'=w)
    float ca = 0.0f, cb = 0.0f;      // pending L1 x-halves from even i
    #pragma unroll
    for (int i = 0; i < 8; ++i) {
        float4 v = *(const float4*)(tbase + i * 16384);
        accum9(acc, v.x); accum9(acc, v.y); accum9(acc, v.z); accum9(acc, v.w);
        float a = v.x + v.y, b = v.z + v.w;    // x-paired halves
        a += __shfl_xor(a, 32, 64);            // y-pair merge (partner lane l^32)
        b += __shfl_xor(b, 32, 64);
        if ((i & 1) == 0) { ca = a; cb = b; }
        else {
            float A = ca + a, B = cb + b;      // L1 cells (2*x5, w, i>>1), (2*x5+1, ...)
            accum9(acc + 9, A); accum9(acc + 9, B);
            if (i < 4) d0 += A + B; else d1 += A + B;
        }
    }
    #pragma unroll
    for (int j = 9; j < 18; ++j) acc[j] *= 0.5f;   // L1 replicated on yb lane pairs

    if ((l >> 5) == 0) {             // one writer per replica pair
        zm[w * 64 + x5]      = d0;
        zm[w * 64 + 32 + x5] = d1;
    }
    __syncthreads();

    // L2: 32(x) x 2(y'') x 2(z'') = 128 cells; y''-pairs are w-pairs
    if (t < 128) {
        int x = t & 31, zpp = (t >> 5) & 1, ypp = t >> 6;
        float s = zm[(2 * ypp) * 64 + zpp * 32 + x] + zm[(2 * ypp + 1) * 64 + zpp * 32 + x];
        accum9(acc + 18, s);
    }
    // L3: 16 cells, each = 16 zm entries (all w, z'', x-pair)
    if (t < 16) {
        float s = 0.0f;
        #pragma unroll
        for (int q = 0; q < 8; ++q)   // q = w*2 + z''
            s += zm[q * 32 + 2 * t] + zm[q * 32 + 2 * t + 1];
        accum9(acc + 27, s);
        l3map[(size_t)ch * 4096 + rz * 256 + ry * 16 + t] = s;
    }

    block_reduce<36>(acc, red, t);
    if (t < 36)
        part[((size_t)ch * 36 + t) * 256 + r] =
            red[t] + red[36 + t] + red[72 + t] + red[108 + t];

    // ---- fan-in: release part/l3map writes, last block per channel finishes ----
    __threadfence();                 // order this thread's global stores (device scope)
    __syncthreads();                 // all fences done before the ticket
    if (t == 0) last = (atomicAdd(&cnt[ch], 1) == 255);
    __syncthreads();
    if (!last) return;
    __threadfence();                 // acquire: see all 256 blocks' part/l3map

    // ================= finisher (old k_pyr body, channel ch) =================
    // ---- levels 0-3 from block partials (coalesced, 1 load/thread/stat) ----
    float facc[36];
    #pragma unroll
    for (int j = 0; j < 36; ++j)
        facc[j] = part[((size_t)ch * 36 + j) * 256 + t];
    block_reduce<36>(facc, red, t);
    if (t < 36) sst[t] = red[t] + red[36 + t] + red[72 + t] + red[108 + t];
    __syncthreads();

    // ---- level 4: pool l3map 16^3 -> 8^3 ----
    const float2* L3 = (const float2*)(l3map + (size_t)ch * 4096);
    float a9[9];
    #pragma unroll
    for (int j = 0; j < 9; ++j) a9[j] = 0.0f;
    #pragma unroll
    for (int i = 0; i < 2; ++i) {
        int c = t + i * 256;
        int x = c & 7, yy = (c >> 3) & 7, z = c >> 6;
        const float2* p = L3 + z * 256 + yy * 16 + x;   // f2 idx = 2z*128 + 2y*8 + x
        float2 b0 = p[0], b1 = p[8], b2 = p[128], b3 = p[136];
        float s = (b0.x + b0.y) + (b1.x + b1.y) + (b2.x + b2.y) + (b3.x + b3.y);
        M4[c] = s;
        accum9(a9, s);
    }
    __syncthreads();
    block_reduce<9>(a9, red, t);
    if (t < 9) sst[36 + t] = red[t] + red[9 + t] + red[18 + t] + red[27 + t];
    __syncthreads();

    // ---- level 5: pool M4 8^3 -> 4^3 ----
    float c9[9];
    #pragma unroll
    for (int j = 0; j < 9; ++j) c9[j] = 0.0f;
    if (t < 64) {
        int x = t & 3, yy = (t >> 2) & 3, z = t >> 4;
        const float2* p = (const float2*)M4 + z * 64 + yy * 8 + x;  // 2z*32 + 2y*4 + x
        float2 b0 = p[0], b1 = p[4], b2 = p[32], b3 = p[36];
        float s = (b0.x + b0.y) + (b1.x + b1.y) + (b2.x + b2.y) + (b3.x + b3.y);
        accum9(c9, s);
    }
    __syncthreads();
    block_reduce<9>(c9, red, t);
    if (t < 9) sst[45 + t] = red[t] + red[9 + t] + red[18 + t] + red[27 + t];
    __syncthreads();

    // ---- finale: least-squares slope, double precision, 8 outputs ----
    if (t < 8) {
        int k = bounds[t];
        const double LN2 = 0.6931471805599453094;
        double b  = (double)sst[3];          // S_1 at level 0 == total sum
        double lb = log(b);
        double num = 0.0;
        #pragma unroll
        for (int s = 0; s < 6; ++s) {
            const float* st = sst + s * 9;
            double p;
            if (k == 1) p = ((double)st[8] - lb * (double)st[3]) / b;
            else        p = log((double)st[k + 2]) - (double)k * lb;
            num += (6.0 * s - 15.0) * LN2 * p;   // n*q_s - qs
        }
        double den = 105.0 * LN2 * LN2;          // n*q2s - qs^2
        double aa  = (k == 1) ? 1.0 : 1.0 / (double)(k - 1);
        out[ch * 8 + t] = (float)(aa * num / den);
    }
}

extern "C" void kernel_launch(void* const* d_in, const int* in_sizes, int n_in,
                              void* d_out, int out_size, void* d_ws, size_t ws_size,
                              hipStream_t stream) {
    const float* img    = (const float*)d_in[0];
    const int*   bounds = (const int*)d_in[1];
    float*       out    = (float*)d_out;
    float*       ws     = (float*)d_ws;

    // ws layout (floats): part[6*36*256=55296] @0, l3map[6*4096=24576] @55296,
    // cnt[6 ints] @79872. ws is poisoned each iteration -> counters must be
    // zeroed here (async memset is graph-capturable; no banned calls).
    float* part  = ws;
    float* l3map = ws + 55296;
    int*   cnt   = (int*)(ws + 55296 + 24576);

    hipMemsetAsync(cnt, 0, 6 * sizeof(int), stream);
    k_fused<<<dim3(256, 6), 256, 0, stream>>>(img, part, l3map, cnt, bounds, out);
}

// Round 2
// 130.967 us; speedup vs baseline: 1.8322x; 1.8322x over previous
//
#include <hip/hip_runtime.h>

#define CHVOL (128*128*128)

// Agent-scope (device-coherent) relaxed load/store: compiles to global_load/
// global_store with sc flags -> reads/writes the Infinity-Cache coherence
// point, bypassing non-coherent per-XCD L2 / per-CU L1. No buffer_wbl2.
#define ST_AG(p, v) __hip_atomic_store((p), (v), __ATOMIC_RELAXED, __HIP_MEMORY_SCOPE_AGENT)
#define LD_AG(p)    __hip_atomic_load((p), __ATOMIC_RELAXED, __HIP_MEMORY_SCOPE_AGENT)

// 9 stats: [S_-2, S_-1, S_0(count), S_1, S_2, S_3, S_4, S_5, T=sum x*ln x]
// Branchless: cndmask + fma, no divergent branch.
__device__ __forceinline__ void accum9(float* a, float x) {
    bool nz = (x != 0.0f);
    float u = nz ? __builtin_amdgcn_rcpf(x) : 0.0f;
    float l = nz ? __logf(x) : 0.0f;
    float x2 = x * x;
    float x4 = x2 * x2;
    a[0] = fmaf(u, u, a[0]);
    a[1] += u;
    a[2] += nz ? 1.0f : 0.0f;
    a[3] += x;
    a[4] += x2;
    a[5] = fmaf(x2, x, a[5]);
    a[6] += x4;
    a[7] = fmaf(x4, x, a[7]);
    a[8] = fmaf(x, l, a[8]);
}

// Shuffle-reduce NS stats across the block; leaves 4 per-wave partials in red.
// Caller combines red[t] + red[NS+t] + red[2NS+t] + red[3NS+t] after the sync.
template<int NS>
__device__ __forceinline__ void block_reduce(float* acc, float* red, int t) {
    #pragma unroll
    for (int s = 0; s < NS; ++s) {
        float v = acc[s];
        v += __shfl_down(v, 32, 64);
        v += __shfl_down(v, 16, 64);
        v += __shfl_down(v, 8, 64);
        v += __shfl_down(v, 4, 64);
        v += __shfl_down(v, 2, 64);
        v += __shfl_down(v, 1, 64);
        if ((t & 63) == 0) red[(t >> 6) * NS + s] = v;
    }
    __syncthreads();
}

// Fused: main pass (levels 0-3 in-block) + per-channel device fan-in.
// Cross-block data (part, l3map) moves via agent-scope stores/loads; the
// ticket is a plain device-scope atomicAdd. No __threadfence / buffer_wbl2.
__global__ __launch_bounds__(256) void k_fused(const float* __restrict__ img,
                                               float* __restrict__ part,
                                               float* __restrict__ l3map,
                                               int* __restrict__ cnt,
                                               const int* __restrict__ bounds,
                                               float* __restrict__ out) {
    __shared__ float zm[256];        // [w4][z''2][x32]
    __shared__ float red[36 * 4];
    __shared__ float sst[54];
    __shared__ float M4[512];
    __shared__ int last;

    const int t  = threadIdx.x;
    const int l  = t & 63, w = t >> 6;
    const int r  = blockIdx.x;        // 0..255
    const int ch = blockIdx.y;        // 0..5
    const int ry = r & 15, rz = r >> 4;
    const float* base = img + (size_t)ch * CHVOL + rz * (8 * 16384) + ry * (8 * 128);

    float acc[36];
    #pragma unroll
    for (int j = 0; j < 36; ++j) acc[j] = 0.0f;

    const int x5 = l & 31;
    const int y  = ((l >> 5) & 1) | (w << 1);   // y in [0,8)
    const float* tbase = base + y * 128 + x5 * 4;

    // Prefetch all 8 z-slice float4s first: 8-deep MLP per wave covers the
    // ~500cy L3-hit latency instead of one load->use stall per iteration.
    // All indices compile-time constant after unroll (no scratch spill).
    float4 v[8];
    #pragma unroll
    for (int i = 0; i < 8; ++i) v[i] = *(const float4*)(tbase + i * 16384);

    // i = z slice 0..7. L1 z-pairs merge across (i, i+1); L2 z''-pairs across i-pairs.
    float d0 = 0.0f, d1 = 0.0f;      // L2 partial for z''=0 / z''=1 at (x''=x5, y'=w)
    float ca = 0.0f, cb = 0.0f;      // pending L1 x-halves from even i
    #pragma unroll
    for (int i = 0; i < 8; ++i) {
        accum9(acc, v[i].x); accum9(acc, v[i].y); accum9(acc, v[i].z); accum9(acc, v[i].w);
        float a = v[i].x + v[i].y, b = v[i].z + v[i].w;    // x-paired halves
        a += __shfl_xor(a, 32, 64);            // y-pair merge (partner lane l^32)
        b += __shfl_xor(b, 32, 64);
        if ((i & 1) == 0) { ca = a; cb = b; }
        else {
            float A = ca + a, B = cb + b;      // L1 cells (2*x5, w, i>>1), (2*x5+1, ...)
            accum9(acc + 9, A); accum9(acc + 9, B);
            if (i < 4) d0 += A + B; else d1 += A + B;
        }
    }
    #pragma unroll
    for (int j = 9; j < 18; ++j) acc[j] *= 0.5f;   // L1 replicated on yb lane pairs

    if ((l >> 5) == 0) {             // one writer per replica pair
        zm[w * 64 + x5]      = d0;
        zm[w * 64 + 32 + x5] = d1;
    }
    __syncthreads();

    // L2: 32(x) x 2(y'') x 2(z'') = 128 cells; y''-pairs are w-pairs
    if (t < 128) {
        int x = t & 31, zpp = (t >> 5) & 1, ypp = t >> 6;
        float s = zm[(2 * ypp) * 64 + zpp * 32 + x] + zm[(2 * ypp + 1) * 64 + zpp * 32 + x];
        accum9(acc + 18, s);
    }
    // L3: 16 cells, each = 16 zm entries (all w, z'', x-pair)
    if (t < 16) {
        float s = 0.0f;
        #pragma unroll
        for (int q = 0; q < 8; ++q)   // q = w*2 + z''
            s += zm[q * 32 + 2 * t] + zm[q * 32 + 2 * t + 1];
        accum9(acc + 27, s);
        ST_AG(&l3map[(size_t)ch * 4096 + rz * 256 + ry * 16 + t], s);
    }

    block_reduce<36>(acc, red, t);
    if (t < 36)
        ST_AG(&part[((size_t)ch * 36 + t) * 256 + r],
              red[t] + red[36 + t] + red[72 + t] + red[108 + t]);

    // ---- fan-in ticket. __syncthreads() drains vmcnt(0): the agent-scope
    // stores above have reached the coherence point before the ticket bumps.
    __syncthreads();
    if (t == 0) last = (atomicAdd(&cnt[ch], 1) == 255);
    __syncthreads();
    if (!last) return;

    // ================= finisher (one block per channel) =================
    // ---- levels 0-3 from block partials (coalesced, 1 load/thread/stat) ----
    float facc[36];
    #pragma unroll
    for (int j = 0; j < 36; ++j)
        facc[j] = LD_AG(&part[((size_t)ch * 36 + j) * 256 + t]);
    block_reduce<36>(facc, red, t);
    if (t < 36) sst[t] = red[t] + red[36 + t] + red[72 + t] + red[108 + t];
    __syncthreads();

    // ---- level 4: pool l3map 16^3 -> 8^3 ----
    const float* L3 = l3map + (size_t)ch * 4096;
    float a9[9];
    #pragma unroll
    for (int j = 0; j < 9; ++j) a9[j] = 0.0f;
    #pragma unroll
    for (int i = 0; i < 2; ++i) {
        int c = t + i * 256;
        int x = c & 7, yy = (c >> 3) & 7, z = c >> 6;
        const float* p = L3 + z * 512 + yy * 32 + x * 2;  // float idx = 2z*256+2y*16+2x
        float s = (LD_AG(p + 0)   + LD_AG(p + 1))
                + (LD_AG(p + 16)  + LD_AG(p + 17))
                + (LD_AG(p + 256) + LD_AG(p + 257))
                + (LD_AG(p + 272) + LD_AG(p + 273));
        M4[c] = s;
        accum9(a9, s);
    }
    __syncthreads();
    block_reduce<9>(a9, red, t);
    if (t < 9) sst[36 + t] = red[t] + red[9 + t] + red[18 + t] + red[27 + t];
    __syncthreads();

    // ---- level 5: pool M4 8^3 -> 4^3 ----
    float c9[9];
    #pragma unroll
    for (int j = 0; j < 9; ++j) c9[j] = 0.0f;
    if (t < 64) {
        int x = t & 3, yy = (t >> 2) & 3, z = t >> 4;
        const float2* p = (const float2*)M4 + z * 64 + yy * 8 + x;  // 2z*32 + 2y*4 + x
        float2 b0 = p[0], b1 = p[4], b2 = p[32], b3 = p[36];
        float s = (b0.x + b0.y) + (b1.x + b1.y) + (b2.x + b2.y) + (b3.x + b3.y);
        accum9(c9, s);
    }
    __syncthreads();
    block_reduce<9>(c9, red, t);
    if (t < 9) sst[45 + t] = red[t] + red[9 + t] + red[18 + t] + red[27 + t];
    __syncthreads();

    // ---- finale: least-squares slope, double precision, 8 outputs ----
    if (t < 8) {
        int k = bounds[t];
        const double LN2 = 0.6931471805599453094;
        double b  = (double)sst[3];          // S_1 at level 0 == total sum
        double lb = log(b);
        double num = 0.0;
        #pragma unroll
        for (int s = 0; s < 6; ++s) {
            const float* st = sst + s * 9;
            double p;
            if (k == 1) p = ((double)st[8] - lb * (double)st[3]) / b;
            else        p = log((double)st[k + 2]) - (double)k * lb;
            num += (6.0 * s - 15.0) * LN2 * p;   // n*q_s - qs
        }
        double den = 105.0 * LN2 * LN2;          // n*q2s - qs^2
        double aa  = (k == 1) ? 1.0 : 1.0 / (double)(k - 1);
        out[ch * 8 + t] = (float)(aa * num / den);
    }
}

extern "C" void kernel_launch(void* const* d_in, const int* in_sizes, int n_in,
                              void* d_out, int out_size, void* d_ws, size_t ws_size,
                              hipStream_t stream) {
    const float* img    = (const float*)d_in[0];
    const int*   bounds = (const int*)d_in[1];
    float*       out    = (float*)d_out;
    float*       ws     = (float*)d_ws;

    // ws layout (floats): part[6*36*256=55296] @0, l3map[6*4096=24576] @55296,
    // cnt[6 ints] @79872. ws is poisoned each iteration -> counters zeroed here
    // (async memset is graph-capturable; no banned calls).
    float* part  = ws;
    float* l3map = ws + 55296;
    int*   cnt   = (int*)(ws + 55296 + 24576);

    hipMemsetAsync(cnt, 0, 6 * sizeof(int), stream);
    k_fused<<<dim3(256, 6), 256, 0, stream>>>(img, part, l3map, cnt, bounds, out);
}

// Round 3
// 124.396 us; speedup vs baseline: 1.9290x; 1.0528x over previous
//
#include <hip/hip_runtime.h>

#define CHVOL (128*128*128)

// Agent-scope (device-coherent) relaxed load/store: global_load/store with sc
// flags -> reads/writes the coherence point, bypassing non-coherent per-XCD
// L2 / per-CU L1. No buffer_wbl2, no RMW.
#define ST_AG(p, v) __hip_atomic_store((p), (v), __ATOMIC_RELAXED, __HIP_MEMORY_SCOPE_AGENT)
#define LD_AG(p)    __hip_atomic_load((p), __ATOMIC_RELAXED, __HIP_MEMORY_SCOPE_AGENT)

// 9 stats: [S_-2, S_-1, S_0(count), S_1, S_2, S_3, S_4, S_5, T=sum x*ln x]
// Branchless: cndmask + fma, no divergent branch.
__device__ __forceinline__ void accum9(float* a, float x) {
    bool nz = (x != 0.0f);
    float u = nz ? __builtin_amdgcn_rcpf(x) : 0.0f;
    float l = nz ? __logf(x) : 0.0f;
    float x2 = x * x;
    float x4 = x2 * x2;
    a[0] = fmaf(u, u, a[0]);
    a[1] += u;
    a[2] += nz ? 1.0f : 0.0f;
    a[3] += x;
    a[4] += x2;
    a[5] = fmaf(x2, x, a[5]);
    a[6] += x4;
    a[7] = fmaf(x4, x, a[7]);
    a[8] = fmaf(x, l, a[8]);
}

// Shuffle-reduce NS stats across the block; leaves 4 per-wave partials in red.
// Caller combines red[t] + red[NS+t] + red[2NS+t] + red[3NS+t] after the sync.
template<int NS>
__device__ __forceinline__ void block_reduce(float* acc, float* red, int t) {
    #pragma unroll
    for (int s = 0; s < NS; ++s) {
        float v = acc[s];
        v += __shfl_down(v, 32, 64);
        v += __shfl_down(v, 16, 64);
        v += __shfl_down(v, 8, 64);
        v += __shfl_down(v, 4, 64);
        v += __shfl_down(v, 2, 64);
        v += __shfl_down(v, 1, 64);
        if ((t & 63) == 0) red[(t >> 6) * NS + s] = v;
    }
    __syncthreads();
}

// Fused: main pass (levels 0-3 in-block) + per-channel fan-in via
// contention-free completion flags (one relaxed agent store per block, no
// same-address atomics). Block r==0 of each channel spins on the 256 flags,
// then runs the finisher with plain cached loads after an acquire fence.
__global__ __launch_bounds__(256) void k_fused(const float* __restrict__ img,
                                               float* __restrict__ part,
                                               float* __restrict__ l3map,
                                               int* __restrict__ flg,
                                               const int* __restrict__ bounds,
                                               float* __restrict__ out) {
    __shared__ float zm[256];        // [w4][z''2][x32]
    __shared__ float red[36 * 4];
    __shared__ float sst[54];
    __shared__ float M4[512];

    const int t  = threadIdx.x;
    const int l  = t & 63, w = t >> 6;
    const int r  = blockIdx.x;        // 0..255
    const int ch = blockIdx.y;        // 0..5
    const int ry = r & 15, rz = r >> 4;
    const float* base = img + (size_t)ch * CHVOL + rz * (8 * 16384) + ry * (8 * 128);

    float acc[36];
    #pragma unroll
    for (int j = 0; j < 36; ++j) acc[j] = 0.0f;

    const int x5 = l & 31;
    const int y  = ((l >> 5) & 1) | (w << 1);   // y in [0,8)
    const float* tbase = base + y * 128 + x5 * 4;

    // Prefetch all 8 z-slice float4s: 8-deep MLP per wave covers load latency.
    float4 v[8];
    #pragma unroll
    for (int i = 0; i < 8; ++i) v[i] = *(const float4*)(tbase + i * 16384);

    // i = z slice 0..7. L1 z-pairs merge across (i, i+1); L2 z''-pairs across i-pairs.
    float d0 = 0.0f, d1 = 0.0f;      // L2 partial for z''=0 / z''=1 at (x''=x5, y'=w)
    float ca = 0.0f, cb = 0.0f;      // pending L1 x-halves from even i
    #pragma unroll
    for (int i = 0; i < 8; ++i) {
        accum9(acc, v[i].x); accum9(acc, v[i].y); accum9(acc, v[i].z); accum9(acc, v[i].w);
        float a = v[i].x + v[i].y, b = v[i].z + v[i].w;    // x-paired halves
        a += __shfl_xor(a, 32, 64);            // y-pair merge (partner lane l^32)
        b += __shfl_xor(b, 32, 64);
        if ((i & 1) == 0) { ca = a; cb = b; }
        else {
            float A = ca + a, B = cb + b;      // L1 cells (2*x5, w, i>>1), (2*x5+1, ...)
            accum9(acc + 9, A); accum9(acc + 9, B);
            if (i < 4) d0 += A + B; else d1 += A + B;
        }
    }
    #pragma unroll
    for (int j = 9; j < 18; ++j) acc[j] *= 0.5f;   // L1 replicated on yb lane pairs

    if ((l >> 5) == 0) {             // one writer per replica pair
        zm[w * 64 + x5]      = d0;
        zm[w * 64 + 32 + x5] = d1;
    }
    __syncthreads();

    // L2: 32(x) x 2(y'') x 2(z'') = 128 cells; y''-pairs are w-pairs
    if (t < 128) {
        int x = t & 31, zpp = (t >> 5) & 1, ypp = t >> 6;
        float s = zm[(2 * ypp) * 64 + zpp * 32 + x] + zm[(2 * ypp + 1) * 64 + zpp * 32 + x];
        accum9(acc + 18, s);
    }
    // L3: 16 cells, each = 16 zm entries (all w, z'', x-pair)
    if (t < 16) {
        float s = 0.0f;
        #pragma unroll
        for (int q = 0; q < 8; ++q)   // q = w*2 + z''
            s += zm[q * 32 + 2 * t] + zm[q * 32 + 2 * t + 1];
        accum9(acc + 27, s);
        ST_AG(&l3map[(size_t)ch * 4096 + rz * 256 + ry * 16 + t], s);
    }

    block_reduce<36>(acc, red, t);
    if (t < 36)
        ST_AG(&part[((size_t)ch * 36 + t) * 256 + r],
              red[t] + red[36 + t] + red[72 + t] + red[108 + t]);

    // ---- completion flag. __syncthreads() drains vmcnt(0) per wave: the
    // sc1 data stores above reached the coherence point before the flag.
    __syncthreads();
    if (t == 0) ST_AG(&flg[ch * 256 + r], 1);
    if (r != 0) return;

    // ---- spinner: thread t waits for block t's flag (distinct addresses,
    // no RMW -> no same-address serialization storm).
    while (LD_AG(&flg[ch * 256 + t]) == 0) __builtin_amdgcn_s_sleep(2);
    __builtin_amdgcn_fence(__ATOMIC_ACQUIRE, "agent");   // inv L1/L2 (no writeback)
    __syncthreads();

    // ================= finisher (one block per channel) =================
    // ---- levels 0-3 from block partials (coalesced, plain cached loads) ----
    float facc[36];
    #pragma unroll
    for (int j = 0; j < 36; ++j)
        facc[j] = part[((size_t)ch * 36 + j) * 256 + t];
    block_reduce<36>(facc, red, t);
    if (t < 36) sst[t] = red[t] + red[36 + t] + red[72 + t] + red[108 + t];
    __syncthreads();

    // ---- level 4: pool l3map 16^3 -> 8^3 ----
    const float2* L3 = (const float2*)(l3map + (size_t)ch * 4096);
    float a9[9];
    #pragma unroll
    for (int j = 0; j < 9; ++j) a9[j] = 0.0f;
    #pragma unroll
    for (int i = 0; i < 2; ++i) {
        int c = t + i * 256;
        int x = c & 7, yy = (c >> 3) & 7, z = c >> 6;
        const float2* p = L3 + z * 256 + yy * 16 + x;   // f2 idx = 2z*128 + 2y*8 + x
        float2 b0 = p[0], b1 = p[8], b2 = p[128], b3 = p[136];
        float s = (b0.x + b0.y) + (b1.x + b1.y) + (b2.x + b2.y) + (b3.x + b3.y);
        M4[c] = s;
        accum9(a9, s);
    }
    __syncthreads();
    block_reduce<9>(a9, red, t);
    if (t < 9) sst[36 + t] = red[t] + red[9 + t] + red[18 + t] + red[27 + t];
    __syncthreads();

    // ---- level 5: pool M4 8^3 -> 4^3 ----
    float c9[9];
    #pragma unroll
    for (int j = 0; j < 9; ++j) c9[j] = 0.0f;
    if (t < 64) {
        int x = t & 3, yy = (t >> 2) & 3, z = t >> 4;
        const float2* p = (const float2*)M4 + z * 64 + yy * 8 + x;  // 2z*32 + 2y*4 + x
        float2 b0 = p[0], b1 = p[4], b2 = p[32], b3 = p[36];
        float s = (b0.x + b0.y) + (b1.x + b1.y) + (b2.x + b2.y) + (b3.x + b3.y);
        accum9(c9, s);
    }
    __syncthreads();
    block_reduce<9>(c9, red, t);
    if (t < 9) sst[45 + t] = red[t] + red[9 + t] + red[18 + t] + red[27 + t];
    __syncthreads();

    // ---- finale: least-squares slope, double precision, 8 outputs ----
    if (t < 8) {
        int k = bounds[t];
        const double LN2 = 0.6931471805599453094;
        double b  = (double)sst[3];          // S_1 at level 0 == total sum
        double lb = log(b);
        double num = 0.0;
        #pragma unroll
        for (int s = 0; s < 6; ++s) {
            const float* st = sst + s * 9;
            double p;
            if (k == 1) p = ((double)st[8] - lb * (double)st[3]) / b;
            else        p = log((double)st[k + 2]) - (double)k * lb;
            num += (6.0 * s - 15.0) * LN2 * p;   // n*q_s - qs
        }
        double den = 105.0 * LN2 * LN2;          // n*q2s - qs^2
        double aa  = (k == 1) ? 1.0 : 1.0 / (double)(k - 1);
        out[ch * 8 + t] = (float)(aa * num / den);
    }
}

extern "C" void kernel_launch(void* const* d_in, const int* in_sizes, int n_in,
                              void* d_out, int out_size, void* d_ws, size_t ws_size,
                              hipStream_t stream) {
    const float* img    = (const float*)d_in[0];
    const int*   bounds = (const int*)d_in[1];
    float*       out    = (float*)d_out;
    float*       ws     = (float*)d_ws;

    // ws layout (floats): part[6*36*256=55296] @0, l3map[6*4096=24576] @55296,
    // flg[6*256 ints] @79872. ws is poisoned each iteration -> flags zeroed
    // here (async memset is graph-capturable; no banned calls).
    float* part  = ws;
    float* l3map = ws + 55296;
    int*   flg   = (int*)(ws + 55296 + 24576);

    hipMemsetAsync(flg, 0, 6 * 256 * sizeof(int), stream);
    k_fused<<<dim3(256, 6), 256, 0, stream>>>(img, part, l3map, flg, bounds, out);
}

// Round 4
// 123.668 us; speedup vs baseline: 1.9404x; 1.0059x over previous
//
#include <hip/hip_runtime.h>

#define CHVOL (128*128*128)

// Agent-scope (device-coherent) relaxed load/store: L2-bypassing access to
// the coherence point. All sc1 STORES below are line-private per block
// (no two blocks write the same 64-B line) to avoid same-line write-through
// serialization at the IF home node.
#define ST_AG(p, v) __hip_atomic_store((p), (v), __ATOMIC_RELAXED, __HIP_MEMORY_SCOPE_AGENT)
#define LD_AG(p)    __hip_atomic_load((p), __ATOMIC_RELAXED, __HIP_MEMORY_SCOPE_AGENT)

// part stride: 48 floats = 192 B = exactly 3 cache lines per block.
#define PSTR 48

// 9 stats: [S_-2, S_-1, S_0(count), S_1, S_2, S_3, S_4, S_5, T=sum x*ln x]
__device__ __forceinline__ void accum9(float* a, float x) {
    bool nz = (x != 0.0f);
    float u = nz ? __builtin_amdgcn_rcpf(x) : 0.0f;
    float l = nz ? __logf(x) : 0.0f;
    float x2 = x * x;
    float x4 = x2 * x2;
    a[0] = fmaf(u, u, a[0]);
    a[1] += u;
    a[2] += nz ? 1.0f : 0.0f;
    a[3] += x;
    a[4] += x2;
    a[5] = fmaf(x2, x, a[5]);
    a[6] += x4;
    a[7] = fmaf(x4, x, a[7]);
    a[8] = fmaf(x, l, a[8]);
}

// Shuffle-reduce NS stats across the block; leaves 4 per-wave partials in red.
template<int NS>
__device__ __forceinline__ void block_reduce(float* acc, float* red, int t) {
    #pragma unroll
    for (int s = 0; s < NS; ++s) {
        float v = acc[s];
        v += __shfl_down(v, 32, 64);
        v += __shfl_down(v, 16, 64);
        v += __shfl_down(v, 8, 64);
        v += __shfl_down(v, 4, 64);
        v += __shfl_down(v, 2, 64);
        v += __shfl_down(v, 1, 64);
        if ((t & 63) == 0) red[(t >> 6) * NS + s] = v;
    }
    __syncthreads();
}

__global__ __launch_bounds__(256) void k_fused(const float* __restrict__ img,
                                               float* __restrict__ part,
                                               float* __restrict__ l3map,
                                               int* __restrict__ flg,
                                               const int* __restrict__ bounds,
                                               float* __restrict__ out) {
    __shared__ float zm[256];        // [w4][z''2][x32]
    __shared__ float red[36 * 4];
    __shared__ float sst[54];
    __shared__ float M4[512];

    const int t  = threadIdx.x;
    const int l  = t & 63, w = t >> 6;
    const int r  = blockIdx.x;        // 0..255
    const int ch = blockIdx.y;        // 0..5
    const int ry = r & 15, rz = r >> 4;
    const float* base = img + (size_t)ch * CHVOL + rz * (8 * 16384) + ry * (8 * 128);

    float acc[36];
    #pragma unroll
    for (int j = 0; j < 36; ++j) acc[j] = 0.0f;

    const int x5 = l & 31;
    const int y  = ((l >> 5) & 1) | (w << 1);   // y in [0,8)
    const float* tbase = base + y * 128 + x5 * 4;

    // Prefetch all 8 z-slice float4s: 8-deep MLP per wave covers load latency.
    float4 v[8];
    #pragma unroll
    for (int i = 0; i < 8; ++i) v[i] = *(const float4*)(tbase + i * 16384);

    // L1 z-pairs merge across (i, i+1); L2 z''-pairs across i-pairs.
    float d0 = 0.0f, d1 = 0.0f;      // L2 partial for z''=0 / z''=1 at (x''=x5, y'=w)
    float ca = 0.0f, cb = 0.0f;      // pending L1 x-halves from even i
    #pragma unroll
    for (int i = 0; i < 8; ++i) {
        accum9(acc, v[i].x); accum9(acc, v[i].y); accum9(acc, v[i].z); accum9(acc, v[i].w);
        float a = v[i].x + v[i].y, b = v[i].z + v[i].w;    // x-paired halves
        a += __shfl_xor(a, 32, 64);            // y-pair merge (partner lane l^32)
        b += __shfl_xor(b, 32, 64);
        if ((i & 1) == 0) { ca = a; cb = b; }
        else {
            float A = ca + a, B = cb + b;      // L1 cells (2*x5, w, i>>1), (2*x5+1, ...)
            accum9(acc + 9, A); accum9(acc + 9, B);
            if (i < 4) d0 += A + B; else d1 += A + B;
        }
    }
    #pragma unroll
    for (int j = 9; j < 18; ++j) acc[j] *= 0.5f;   // L1 replicated on yb lane pairs

    if ((l >> 5) == 0) {             // one writer per replica pair
        zm[w * 64 + x5]      = d0;
        zm[w * 64 + 32 + x5] = d1;
    }
    __syncthreads();

    // L2: 32(x) x 2(y'') x 2(z'') = 128 cells; y''-pairs are w-pairs
    if (t < 128) {
        int x = t & 31, zpp = (t >> 5) & 1, ypp = t >> 6;
        float s = zm[(2 * ypp) * 64 + zpp * 32 + x] + zm[(2 * ypp + 1) * 64 + zpp * 32 + x];
        accum9(acc + 18, s);
    }
    // L3: 16 cells, each = 16 zm entries (all w, z'', x-pair).
    // l3map line: 16 floats = 64 B, private to this block.
    if (t < 16) {
        float s = 0.0f;
        #pragma unroll
        for (int q = 0; q < 8; ++q)   // q = w*2 + z''
            s += zm[q * 32 + 2 * t] + zm[q * 32 + 2 * t + 1];
        accum9(acc + 27, s);
        ST_AG(&l3map[(size_t)ch * 4096 + rz * 256 + ry * 16 + t], s);
    }

    block_reduce<36>(acc, red, t);
    // Block-major, 3 lines per block, no cross-block line sharing.
    if (t < 36)
        ST_AG(&part[((size_t)ch * 256 + r) * PSTR + t],
              red[t] + red[36 + t] + red[72 + t] + red[108 + t]);

    // ---- completion flag (one line per flag). __syncthreads() drains
    // vmcnt(0) per wave: the sc1 data stores reached the coherence point.
    __syncthreads();
    if (t == 0) ST_AG(&flg[(ch * 256 + r) * 16], 1);
    if (r != 0) return;

    // ---- spinner: thread t waits for block t's flag (distinct lines).
    while (LD_AG(&flg[(ch * 256 + t) * 16]) == 0) __builtin_amdgcn_s_sleep(2);
    __builtin_amdgcn_fence(__ATOMIC_ACQUIRE, "agent");   // inv L1/L2 (no writeback)
    __syncthreads();

    // ================= finisher (one block per channel) =================
    // ---- levels 0-3 from block partials (plain cached loads post-fence) ----
    float facc[36];
    #pragma unroll
    for (int j = 0; j < 36; ++j)
        facc[j] = part[((size_t)ch * 256 + t) * PSTR + j];
    block_reduce<36>(facc, red, t);
    if (t < 36) sst[t] = red[t] + red[36 + t] + red[72 + t] + red[108 + t];
    __syncthreads();

    // ---- level 4: pool l3map 16^3 -> 8^3 ----
    const float2* L3 = (const float2*)(l3map + (size_t)ch * 4096);
    float a9[9];
    #pragma unroll
    for (int j = 0; j < 9; ++j) a9[j] = 0.0f;
    #pragma unroll
    for (int i = 0; i < 2; ++i) {
        int c = t + i * 256;
        int x = c & 7, yy = (c >> 3) & 7, z = c >> 6;
        const float2* p = L3 + z * 256 + yy * 16 + x;   // f2 idx = 2z*128 + 2y*8 + x
        float2 b0 = p[0], b1 = p[8], b2 = p[128], b3 = p[136];
        float s = (b0.x + b0.y) + (b1.x + b1.y) + (b2.x + b2.y) + (b3.x + b3.y);
        M4[c] = s;
        accum9(a9, s);
    }
    __syncthreads();
    block_reduce<9>(a9, red, t);
    if (t < 9) sst[36 + t] = red[t] + red[9 + t] + red[18 + t] + red[27 + t];
    __syncthreads();

    // ---- level 5: pool M4 8^3 -> 4^3 ----
    float c9[9];
    #pragma unroll
    for (int j = 0; j < 9; ++j) c9[j] = 0.0f;
    if (t < 64) {
        int x = t & 3, yy = (t >> 2) & 3, z = t >> 4;
        const float2* p = (const float2*)M4 + z * 64 + yy * 8 + x;  // 2z*32 + 2y*4 + x
        float2 b0 = p[0], b1 = p[4], b2 = p[32], b3 = p[36];
        float s = (b0.x + b0.y) + (b1.x + b1.y) + (b2.x + b2.y) + (b3.x + b3.y);
        accum9(c9, s);
    }
    __syncthreads();
    block_reduce<9>(c9, red, t);
    if (t < 9) sst[45 + t] = red[t] + red[9 + t] + red[18 + t] + red[27 + t];
    __syncthreads();

    // ---- finale: least-squares slope, double precision, 8 outputs ----
    if (t < 8) {
        int k = bounds[t];
        const double LN2 = 0.6931471805599453094;
        double b  = (double)sst[3];          // S_1 at level 0 == total sum
        double lb = log(b);
        double num = 0.0;
        #pragma unroll
        for (int s = 0; s < 6; ++s) {
            const float* st = sst + s * 9;
            double p;
            if (k == 1) p = ((double)st[8] - lb * (double)st[3]) / b;
            else        p = log((double)st[k + 2]) - (double)k * lb;
            num += (6.0 * s - 15.0) * LN2 * p;   // n*q_s - qs
        }
        double den = 105.0 * LN2 * LN2;          // n*q2s - qs^2
        double aa  = (k == 1) ? 1.0 : 1.0 / (double)(k - 1);
        out[ch * 8 + t] = (float)(aa * num / den);
    }
}

extern "C" void kernel_launch(void* const* d_in, const int* in_sizes, int n_in,
                              void* d_out, int out_size, void* d_ws, size_t ws_size,
                              hipStream_t stream) {
    const float* img    = (const float*)d_in[0];
    const int*   bounds = (const int*)d_in[1];
    float*       out    = (float*)d_out;
    float*       ws     = (float*)d_ws;

    // ws layout (floats): part[6*256*48=73728] @0, l3map[6*4096=24576] @73728,
    // flg[6*256*16 ints] @98304. ws is poisoned each iteration -> flags zeroed
    // here (async memset is graph-capturable; no banned calls).
    float* part  = ws;
    float* l3map = ws + 73728;
    int*   flg   = (int*)(ws + 73728 + 24576);

    hipMemsetAsync(flg, 0, 6 * 256 * 16 * sizeof(int), stream);
    k_fused<<<dim3(256, 6), 256, 0, stream>>>(img, part, l3map, flg, bounds, out);
}

// Round 6
// 119.581 us; speedup vs baseline: 2.0067x; 1.0342x over previous
//
#include <hip/hip_runtime.h>

#define CHVOL (128*128*128)

// 9 stats: [S_-2, S_-1, S_0(count), S_1, S_2, S_3, S_4, S_5, T=sum x*ln x]
// Branchless: cndmask + fma, no divergent branch.
__device__ __forceinline__ void accum9(float* a, float x) {
    bool nz = (x != 0.0f);
    float u = nz ? __builtin_amdgcn_rcpf(x) : 0.0f;
    float l = nz ? __logf(x) : 0.0f;
    float x2 = x * x;
    float x4 = x2 * x2;
    a[0] = fmaf(u, u, a[0]);
    a[1] += u;
    a[2] += nz ? 1.0f : 0.0f;
    a[3] += x;
    a[4] += x2;
    a[5] = fmaf(x2, x, a[5]);
    a[6] += x4;
    a[7] = fmaf(x4, x, a[7]);
    a[8] = fmaf(x, l, a[8]);
}

// Shuffle-reduce NS stats across the block; leaves 4 per-wave partials in red.
// Caller combines red[t] + red[NS+t] + red[2NS+t] + red[3NS+t] after the sync.
template<int NS>
__device__ __forceinline__ void block_reduce(float* acc, float* red, int t) {
    #pragma unroll
    for (int s = 0; s < NS; ++s) {
        float v = acc[s];
        v += __shfl_down(v, 32, 64);
        v += __shfl_down(v, 16, 64);
        v += __shfl_down(v, 8, 64);
        v += __shfl_down(v, 4, 64);
        v += __shfl_down(v, 2, 64);
        v += __shfl_down(v, 1, 64);
        if ((t & 63) == 0) red[(t >> 6) * NS + s] = v;
    }
    __syncthreads();
}

// Region = 128(x) x 8(y) x 8(z) = one full-row slab, 8192 elems.
// Levels 0-3 entirely in-block. All 8 z-slice loads prefetched up-front:
// 8-deep MLP per wave covers the global-load latency (this was the round-0
// k_main bottleneck: one dependent 64-KB-stride load per iteration).
__global__ __launch_bounds__(256) void k_main(const float* __restrict__ img,
                                              float* __restrict__ part,
                                              float* __restrict__ l3map) {
    __shared__ float zm[256];        // [w4][z''2][x32]
    __shared__ float red[36 * 4];

    const int t  = threadIdx.x;
    const int l  = t & 63, w = t >> 6;
    const int r  = blockIdx.x;        // 0..255
    const int ch = blockIdx.y;        // 0..5
    const int ry = r & 15, rz = r >> 4;
    const float* base = img + (size_t)ch * CHVOL + rz * (8 * 16384) + ry * (8 * 128);

    float acc[36];
    #pragma unroll
    for (int j = 0; j < 36; ++j) acc[j] = 0.0f;

    const int x5 = l & 31;
    const int y  = ((l >> 5) & 1) | (w << 1);   // y in [0,8)
    const float* tbase = base + y * 128 + x5 * 4;

    // Prefetch all 8 z-slice float4s (compile-time indices -> stays in VGPRs).
    float4 v[8];
    #pragma unroll
    for (int i = 0; i < 8; ++i) v[i] = *(const float4*)(tbase + i * 16384);

    // i = z slice 0..7. L1 z-pairs merge across (i, i+1); L2 z''-pairs across i-pairs.
    float d0 = 0.0f, d1 = 0.0f;      // L2 partial for z''=0 / z''=1 at (x''=x5, y'=w)
    float ca = 0.0f, cb = 0.0f;      // pending L1 x-halves from even i
    #pragma unroll
    for (int i = 0; i < 8; ++i) {
        accum9(acc, v[i].x); accum9(acc, v[i].y); accum9(acc, v[i].z); accum9(acc, v[i].w);
        float a = v[i].x + v[i].y, b = v[i].z + v[i].w;    // x-paired halves
        a += __shfl_xor(a, 32, 64);            // y-pair merge (partner lane l^32)
        b += __shfl_xor(b, 32, 64);
        if ((i & 1) == 0) { ca = a; cb = b; }
        else {
            float A = ca + a, B = cb + b;      // L1 cells (2*x5, w, i>>1), (2*x5+1, ...)
            accum9(acc + 9, A); accum9(acc + 9, B);
            if (i < 4) d0 += A + B; else d1 += A + B;
        }
    }
    #pragma unroll
    for (int j = 9; j < 18; ++j) acc[j] *= 0.5f;   // L1 replicated on yb lane pairs

    if ((l >> 5) == 0) {             // one writer per replica pair
        zm[w * 64 + x5]      = d0;
        zm[w * 64 + 32 + x5] = d1;
    }
    __syncthreads();

    // L2: 32(x) x 2(y'') x 2(z'') = 128 cells; y''-pairs are w-pairs
    if (t < 128) {
        int x = t & 31, zpp = (t >> 5) & 1, ypp = t >> 6;
        float s = zm[(2 * ypp) * 64 + zpp * 32 + x] + zm[(2 * ypp + 1) * 64 + zpp * 32 + x];
        accum9(acc + 18, s);
    }
    // L3: 16 cells, each = 16 zm entries (all w, z'', x-pair)
    if (t < 16) {
        float s = 0.0f;
        #pragma unroll
        for (int q = 0; q < 8; ++q)   // q = w*2 + z''
            s += zm[q * 32 + 2 * t] + zm[q * 32 + 2 * t + 1];
        accum9(acc + 27, s);
        l3map[(size_t)ch * 4096 + rz * 256 + ry * 16 + t] = s;
    }

    block_reduce<36>(acc, red, t);
    if (t < 36)
        part[((size_t)ch * 36 + t) * 256 + r] =
            red[t] + red[36 + t] + red[72 + t] + red[108 + t];
}

// One block per channel: combine 256 block-partials (levels 0-3), pyramid
// 16^3 -> 8^3 -> 4^3 for levels 4,5, then compute the 8 outputs directly.
// Cross-kernel coherence via the runtime's AGENT release/acquire at the
// dispatch boundary (cheap: k_main dirties only ~150 KB of L2).
__global__ __launch_bounds__(256) void k_pyr(const float* __restrict__ part,
                                             const float* __restrict__ l3map,
                                             const int* __restrict__ bounds,
                                             float* __restrict__ out) {
    __shared__ float red[36 * 4];
    __shared__ float sst[54];
    __shared__ float M4[512];

    const int t  = threadIdx.x;
    const int ch = blockIdx.x;

    // ---- levels 0-3 from block partials (coalesced, 1 load/thread/stat) ----
    float acc[36];
    #pragma unroll
    for (int j = 0; j < 36; ++j)
        acc[j] = part[((size_t)ch * 36 + j) * 256 + t];
    block_reduce<36>(acc, red, t);
    if (t < 36) sst[t] = red[t] + red[36 + t] + red[72 + t] + red[108 + t];
    __syncthreads();

    // ---- level 4: pool l3map 16^3 -> 8^3 ----
    const float2* L3 = (const float2*)(l3map + (size_t)ch * 4096);
    float a9[9];
    #pragma unroll
    for (int j = 0; j < 9; ++j) a9[j] = 0.0f;
    #pragma unroll
    for (int i = 0; i < 2; ++i) {
        int c = t + i * 256;
        int x = c & 7, y = (c >> 3) & 7, z = c >> 6;
        const float2* p = L3 + z * 256 + y * 16 + x;   // f2 idx = 2z*128 + 2y*8 + x
        float2 b0 = p[0], b1 = p[8], b2 = p[128], b3 = p[136];
        float s = (b0.x + b0.y) + (b1.x + b1.y) + (b2.x + b2.y) + (b3.x + b3.y);
        M4[c] = s;
        accum9(a9, s);
    }
    __syncthreads();
    block_reduce<9>(a9, red, t);
    if (t < 9) sst[36 + t] = red[t] + red[9 + t] + red[18 + t] + red[27 + t];
    __syncthreads();

    // ---- level 5: pool M4 8^3 -> 4^3 ----
    float c9[9];
    #pragma unroll
    for (int j = 0; j < 9; ++j) c9[j] = 0.0f;
    if (t < 64) {
        int x = t & 3, y = (t >> 2) & 3, z = t >> 4;
        const float2* p = (const float2*)M4 + z * 64 + y * 8 + x;  // 2z*32 + 2y*4 + x
        float2 b0 = p[0], b1 = p[4], b2 = p[32], b3 = p[36];
        float s = (b0.x + b0.y) + (b1.x + b1.y) + (b2.x + b2.y) + (b3.x + b3.y);
        accum9(c9, s);
    }
    __syncthreads();
    block_reduce<9>(c9, red, t);
    if (t < 9) sst[45 + t] = red[t] + red[9 + t] + red[18 + t] + red[27 + t];
    __syncthreads();

    // ---- finale: least-squares slope, double precision, 8 outputs ----
    if (t < 8) {
        int k = bounds[t];
        const double LN2 = 0.6931471805599453094;
        double b  = (double)sst[3];          // S_1 at level 0 == total sum
        double lb = log(b);
        double num = 0.0;
        #pragma unroll
        for (int s = 0; s < 6; ++s) {
            const float* st = sst + s * 9;
            double p;
            if (k == 1) p = ((double)st[8] - lb * (double)st[3]) / b;
            else        p = log((double)st[k + 2]) - (double)k * lb;
            num += (6.0 * s - 15.0) * LN2 * p;   // n*q_s - qs
        }
        double den = 105.0 * LN2 * LN2;          // n*q2s - qs^2
        double aa  = (k == 1) ? 1.0 : 1.0 / (double)(k - 1);
        out[ch * 8 + t] = (float)(aa * num / den);
    }
}

extern "C" void kernel_launch(void* const* d_in, const int* in_sizes, int n_in,
                              void* d_out, int out_size, void* d_ws, size_t ws_size,
                              hipStream_t stream) {
    const float* img    = (const float*)d_in[0];
    const int*   bounds = (const int*)d_in[1];
    float*       out    = (float*)d_out;
    float*       ws     = (float*)d_ws;

    // ws layout (floats): part[6*36*256=55296] @0, l3map[6*4096=24576] @55296.
    float* part  = ws;
    float* l3map = ws + 55296;

    k_main<<<dim3(256, 6), 256, 0, stream>>>(img, part, l3map);
    k_pyr<<<6, 256, 0, stream>>>(part, l3map, bounds, out);
}